// Round 2
// baseline (571.867 us; speedup 1.0000x reference)
//
#include <hip/hip_runtime.h>
#include <hip/hip_bf16.h>
#include <math.h>

#define BATCH 8
#define SQL 4096
#define SKL 4096
#define DIM 256
#define KVB 32

typedef __attribute__((ext_vector_type(8))) short short8;
typedef __attribute__((ext_vector_type(4))) float f32x4;
typedef __attribute__((ext_vector_type(4))) float floatx4;

__device__ __forceinline__ short f2bf(float f) {
  union { float f; unsigned u; } x; x.f = f;
  unsigned r = x.u + 0x7fffu + ((x.u >> 16) & 1u);
  return (short)(r >> 16);
}

// ---------- projection: C[m,n] = X[m,:].W[n,:] + b[n], bf16 row-major out ----------
// block = 256 threads (4 waves); block covers 16 m-rows x 256 n-cols; wave w -> n in [64w, 64w+64)
__global__ __launch_bounds__(256) void proj_kernel(
    const float* __restrict__ X, const float* __restrict__ W,
    const float* __restrict__ bias, short* __restrict__ out)
{
  const int lane = threadIdx.x & 63;
  const int wave = threadIdx.x >> 6;
  const int lr = lane & 15, hi = lane >> 4;
  const int m0 = blockIdx.x * 16;
  const int n0 = wave * 64;

  f32x4 acc[4] = {(f32x4)0.f, (f32x4)0.f, (f32x4)0.f, (f32x4)0.f};
  const float* xrow = X + (size_t)(m0 + lr) * DIM;

  #pragma unroll
  for (int kk = 0; kk < 8; ++kk) {
    const int k8 = kk * 32 + hi * 8;
    floatx4 xa = *(const floatx4*)(xrow + k8);
    floatx4 xb = *(const floatx4*)(xrow + k8 + 4);
    short8 a;
    #pragma unroll
    for (int j = 0; j < 4; ++j) { a[j] = f2bf(xa[j]); a[j+4] = f2bf(xb[j]); }
    #pragma unroll
    for (int nb = 0; nb < 4; ++nb) {
      const float* wrow = W + (size_t)(n0 + nb*16 + lr) * DIM + k8;
      floatx4 wa = *(const floatx4*)(wrow);
      floatx4 wb = *(const floatx4*)(wrow + 4);
      short8 b;
      #pragma unroll
      for (int j = 0; j < 4; ++j) { b[j] = f2bf(wa[j]); b[j+4] = f2bf(wb[j]); }
      acc[nb] = __builtin_amdgcn_mfma_f32_16x16x32_bf16(a, b, acc[nb], 0, 0, 0);
    }
  }
  #pragma unroll
  for (int nb = 0; nb < 4; ++nb) {
    const int n = n0 + nb*16 + lr;
    const float bv = bias[n];
    #pragma unroll
    for (int r = 0; r < 4; ++r) {
      const int m = m0 + hi*4 + r;
      out[(size_t)m * DIM + n] = f2bf(acc[nb][r] + bv);
    }
  }
}

// ---------- V projection, output TRANSPOSED: outT[b][d][k] ----------
__global__ __launch_bounds__(256) void projV_kernel(
    const float* __restrict__ X, const float* __restrict__ W,
    const float* __restrict__ bias, short* __restrict__ outT)
{
  __shared__ short tile[16][264];
  const int lane = threadIdx.x & 63;
  const int wave = threadIdx.x >> 6;
  const int lr = lane & 15, hi = lane >> 4;
  const int m0 = blockIdx.x * 16;
  const int n0 = wave * 64;

  f32x4 acc[4] = {(f32x4)0.f, (f32x4)0.f, (f32x4)0.f, (f32x4)0.f};
  const float* xrow = X + (size_t)(m0 + lr) * DIM;

  #pragma unroll
  for (int kk = 0; kk < 8; ++kk) {
    const int k8 = kk * 32 + hi * 8;
    floatx4 xa = *(const floatx4*)(xrow + k8);
    floatx4 xb = *(const floatx4*)(xrow + k8 + 4);
    short8 a;
    #pragma unroll
    for (int j = 0; j < 4; ++j) { a[j] = f2bf(xa[j]); a[j+4] = f2bf(xb[j]); }
    #pragma unroll
    for (int nb = 0; nb < 4; ++nb) {
      const float* wrow = W + (size_t)(n0 + nb*16 + lr) * DIM + k8;
      floatx4 wa = *(const floatx4*)(wrow);
      floatx4 wb = *(const floatx4*)(wrow + 4);
      short8 b;
      #pragma unroll
      for (int j = 0; j < 4; ++j) { b[j] = f2bf(wa[j]); b[j+4] = f2bf(wb[j]); }
      acc[nb] = __builtin_amdgcn_mfma_f32_16x16x32_bf16(a, b, acc[nb], 0, 0, 0);
    }
  }
  #pragma unroll
  for (int nb = 0; nb < 4; ++nb) {
    const int n = n0 + nb*16 + lr;
    const float bv = bias[n];
    #pragma unroll
    for (int r = 0; r < 4; ++r)
      tile[hi*4 + r][n] = f2bf(acc[nb][r] + bv);
  }
  __syncthreads();
  const int t = threadIdx.x;            // d index 0..255
  short8 lo8, hi8;
  #pragma unroll
  for (int k = 0; k < 8; ++k) { lo8[k] = tile[k][t]; hi8[k] = tile[k+8][t]; }
  const int b  = m0 >> 12;              // 4096 rows per batch
  const int k0 = m0 & (SKL - 1);
  short* p = outT + (size_t)b * DIM * SKL + (size_t)t * SKL + k0;
  *(short8*)(p)     = lo8;
  *(short8*)(p + 8) = hi8;
}

// ---------- flash attention: 4 waves/block, 16 q-rows/wave, KVB=32 ----------
__global__ __launch_bounds__(256) void attn_kernel(
    const short* __restrict__ Qb, const short* __restrict__ Kb,
    const short* __restrict__ VtG, float* __restrict__ out)
{
  __shared__ short Kt[KVB][264];     // K tile, row-major [k][d], padded
  __shared__ short Vt[DIM][40];      // V^T tile [d][k], padded
  __shared__ short Pl[4][16][40];    // per-wave P tile [q][k], padded

  const int tid = threadIdx.x;
  const int lane = tid & 63;
  const int wave = tid >> 6;
  const int lr = lane & 15, hi = lane >> 4;

  const int b  = blockIdx.x >> 6;               // SQ/64 = 64 blocks per batch
  const int q0 = (blockIdx.x & 63) * 64 + wave * 16;

  const short* Qp = Qb  + ((size_t)b * SQL + q0) * DIM;
  const short* Kp = Kb  + (size_t)b * SKL * DIM;
  const short* Vp = VtG + (size_t)b * DIM * SKL;

  short8 qf[8];
  #pragma unroll
  for (int kk = 0; kk < 8; ++kk)
    qf[kk] = *(const short8*)(Qp + (size_t)lr * DIM + kk*32 + hi*8);

  f32x4 o[16];
  #pragma unroll
  for (int i = 0; i < 16; ++i) o[i] = (f32x4)0.f;
  float mrow[4] = {-3.0e38f, -3.0e38f, -3.0e38f, -3.0e38f};
  float lrow[4] = {0.f, 0.f, 0.f, 0.f};

  for (int kv = 0; kv < SKL; kv += KVB) {
    // stage K tile [32][256] (coalesced b128)
    #pragma unroll
    for (int i = 0; i < 4; ++i) {
      const int li = tid + i*256;
      const int row = li >> 5, c8 = (li & 31) * 8;
      short8 v = *(const short8*)(Kp + (size_t)(kv + row) * DIM + c8);
      *(short8*)(&Kt[row][c8]) = v;
    }
    // stage V^T tile [256][32] from pre-transposed global
    #pragma unroll
    for (int i = 0; i < 4; ++i) {
      const int li = tid + i*256;
      const int d = li >> 2, c8 = (li & 3) * 8;
      short8 v = *(const short8*)(Vp + (size_t)d * SKL + kv + c8);
      *(short8*)(&Vt[d][c8]) = v;
    }
    __syncthreads();

    // S = Q K^T  (16 q x 32 k)
    f32x4 s0 = (f32x4)0.f, s1 = (f32x4)0.f;
    #pragma unroll
    for (int kk = 0; kk < 8; ++kk) {
      short8 k0f = *(const short8*)(&Kt[lr     ][kk*32 + hi*8]);
      short8 k1f = *(const short8*)(&Kt[16 + lr][kk*32 + hi*8]);
      s0 = __builtin_amdgcn_mfma_f32_16x16x32_bf16(qf[kk], k0f, s0, 0, 0, 0);
      s1 = __builtin_amdgcn_mfma_f32_16x16x32_bf16(qf[kk], k1f, s1, 0, 0, 0);
    }

    // online softmax (rows live across 16-lane groups: row = hi*4+r, col = lr[+16])
    float scale[4];
    #pragma unroll
    for (int r = 0; r < 4; ++r) {
      float mx = fmaxf(s0[r], s1[r]);
      #pragma unroll
      for (int off = 8; off >= 1; off >>= 1)
        mx = fmaxf(mx, __shfl_xor(mx, off, 64));
      const float mn = fmaxf(mrow[r], mx);
      scale[r] = __expf(mrow[r] - mn);
      const float p0 = __expf(s0[r] - mn);
      const float p1 = __expf(s1[r] - mn);
      s0[r] = p0; s1[r] = p1;
      float ps = p0 + p1;
      #pragma unroll
      for (int off = 8; off >= 1; off >>= 1)
        ps += __shfl_xor(ps, off, 64);
      lrow[r] = lrow[r] * scale[r] + ps;
      mrow[r] = mn;
    }
    #pragma unroll
    for (int dt = 0; dt < 16; ++dt)
      #pragma unroll
      for (int r = 0; r < 4; ++r)
        o[dt][r] *= scale[r];

    // P -> LDS (bf16), re-fragment as MFMA A operand
    #pragma unroll
    for (int r = 0; r < 4; ++r) {
      Pl[wave][hi*4 + r][lr]      = f2bf(s0[r]);
      Pl[wave][hi*4 + r][16 + lr] = f2bf(s1[r]);
    }
    __syncthreads();

    short8 pf = *(const short8*)(&Pl[wave][lr][hi*8]);
    #pragma unroll
    for (int dt = 0; dt < 16; ++dt) {
      short8 vf = *(const short8*)(&Vt[dt*16 + lr][hi*8]);
      o[dt] = __builtin_amdgcn_mfma_f32_16x16x32_bf16(pf, vf, o[dt], 0, 0, 0);
    }
    __syncthreads();
  }

  // epilogue: normalize and store fp32
  float* op = out + ((size_t)b * SQL + q0) * DIM;
  #pragma unroll
  for (int r = 0; r < 4; ++r) {
    const float inv = 1.0f / lrow[r];
    #pragma unroll
    for (int dt = 0; dt < 16; ++dt)
      op[(size_t)(hi*4 + r) * DIM + dt*16 + lr] = o[dt][r] * inv;
  }
}

extern "C" void kernel_launch(void* const* d_in, const int* in_sizes, int n_in,
                              void* d_out, int out_size, void* d_ws, size_t ws_size,
                              hipStream_t stream) {
  const float* query  = (const float*)d_in[0];
  const float* keys   = (const float*)d_in[1];
  const float* values = (const float*)d_in[2];
  const float* Wq = (const float*)d_in[3];
  const float* bq = (const float*)d_in[4];
  const float* Wk = (const float*)d_in[5];
  const float* bk = (const float*)d_in[6];
  const float* Wv = (const float*)d_in[7];
  const float* bv = (const float*)d_in[8];
  float* out = (float*)d_out;

  const size_t elems = (size_t)BATCH * SQL * DIM;   // 8.39M per matrix
  short* Qb  = (short*)d_ws;
  short* Kb  = Qb + elems;
  short* VtT = Kb + elems;                          // [B][D][SK]

  dim3 blk(256, 1, 1);
  proj_kernel <<<dim3(BATCH*SQL/16, 1, 1), blk, 0, stream>>>(query,  Wq, bq, Qb);
  proj_kernel <<<dim3(BATCH*SKL/16, 1, 1), blk, 0, stream>>>(keys,   Wk, bk, Kb);
  projV_kernel<<<dim3(BATCH*SKL/16, 1, 1), blk, 0, stream>>>(values, Wv, bv, VtT);
  attn_kernel <<<dim3(BATCH*SQL/64, 1, 1), blk, 0, stream>>>(Qb, Kb, VtT, out);
}

// Round 3
// 525.806 us; speedup vs baseline: 1.0876x; 1.0876x over previous
//
#include <hip/hip_runtime.h>
#include <hip/hip_bf16.h>
#include <math.h>

#define BATCH 8
#define SQL 4096
#define SKL 4096
#define DIM 256
#define KVB 64
#define NIT (SKL / KVB)

typedef __attribute__((ext_vector_type(8))) short short8;
typedef __attribute__((ext_vector_type(4))) float f32x4;
typedef __attribute__((ext_vector_type(4))) float floatx4;

typedef __attribute__((address_space(3))) unsigned int lds_uint;
typedef __attribute__((address_space(1))) unsigned int glob_uint;

__device__ __forceinline__ void gl_lds16(const void* g, void* l) {
  __builtin_amdgcn_global_load_lds((const glob_uint*)g, (lds_uint*)l, 16, 0, 0);
}

__device__ __forceinline__ short f2bf(float f) {
  union { float f; unsigned u; } x; x.f = f;
  unsigned r = x.u + 0x7fffu + ((x.u >> 16) & 1u);
  return (short)(r >> 16);
}

// ---------- W fp32 -> bf16, once ----------
__global__ __launch_bounds__(256) void wcvt_kernel(
    const float* __restrict__ W0, const float* __restrict__ W1,
    const float* __restrict__ W2, short* __restrict__ out)
{
  const int m = blockIdx.x >> 5;                       // 32 blocks per matrix
  const int i = ((blockIdx.x & 31) * 256 + threadIdx.x) * 8;
  const float* W = (m == 0) ? W0 : ((m == 1) ? W1 : W2);
  floatx4 a = *(const floatx4*)(W + i);
  floatx4 c = *(const floatx4*)(W + i + 4);
  short8 v;
  #pragma unroll
  for (int j = 0; j < 4; ++j) { v[j] = f2bf(a[j]); v[j+4] = f2bf(c[j]); }
  *(short8*)(out + (size_t)m * DIM * DIM + i) = v;
}

// ---------- projection: C[m,n] = X[m,:].Wb[n,:] + b[n], bf16 row-major out ----------
__global__ __launch_bounds__(256) void proj_kernel(
    const float* __restrict__ X, const short* __restrict__ Wb,
    const float* __restrict__ bias, short* __restrict__ out)
{
  const int lane = threadIdx.x & 63;
  const int wave = threadIdx.x >> 6;
  const int lr = lane & 15, hi = lane >> 4;
  const int m0 = blockIdx.x * 16;
  const int n0 = wave * 64;

  f32x4 acc[4] = {(f32x4)0.f, (f32x4)0.f, (f32x4)0.f, (f32x4)0.f};
  const float* xrow = X + (size_t)(m0 + lr) * DIM;

  #pragma unroll
  for (int kk = 0; kk < 8; ++kk) {
    const int k8 = kk * 32 + hi * 8;
    floatx4 xa = *(const floatx4*)(xrow + k8);
    floatx4 xb = *(const floatx4*)(xrow + k8 + 4);
    short8 a;
    #pragma unroll
    for (int j = 0; j < 4; ++j) { a[j] = f2bf(xa[j]); a[j+4] = f2bf(xb[j]); }
    #pragma unroll
    for (int nb = 0; nb < 4; ++nb) {
      short8 bfr = *(const short8*)(Wb + (size_t)(n0 + nb*16 + lr) * DIM + k8);
      acc[nb] = __builtin_amdgcn_mfma_f32_16x16x32_bf16(a, bfr, acc[nb], 0, 0, 0);
    }
  }
  #pragma unroll
  for (int nb = 0; nb < 4; ++nb) {
    const int n = n0 + nb*16 + lr;
    const float bv = bias[n];
    #pragma unroll
    for (int r = 0; r < 4; ++r) {
      const int m = m0 + hi*4 + r;
      out[(size_t)m * DIM + n] = f2bf(acc[nb][r] + bv);
    }
  }
}

// ---------- V projection, output TRANSPOSED: outT[b][d][k] ----------
__global__ __launch_bounds__(256) void projV_kernel(
    const float* __restrict__ X, const short* __restrict__ Wb,
    const float* __restrict__ bias, short* __restrict__ outT)
{
  __shared__ short tile[16][264];
  const int lane = threadIdx.x & 63;
  const int wave = threadIdx.x >> 6;
  const int lr = lane & 15, hi = lane >> 4;
  const int m0 = blockIdx.x * 16;
  const int n0 = wave * 64;

  f32x4 acc[4] = {(f32x4)0.f, (f32x4)0.f, (f32x4)0.f, (f32x4)0.f};
  const float* xrow = X + (size_t)(m0 + lr) * DIM;

  #pragma unroll
  for (int kk = 0; kk < 8; ++kk) {
    const int k8 = kk * 32 + hi * 8;
    floatx4 xa = *(const floatx4*)(xrow + k8);
    floatx4 xb = *(const floatx4*)(xrow + k8 + 4);
    short8 a;
    #pragma unroll
    for (int j = 0; j < 4; ++j) { a[j] = f2bf(xa[j]); a[j+4] = f2bf(xb[j]); }
    #pragma unroll
    for (int nb = 0; nb < 4; ++nb) {
      short8 bfr = *(const short8*)(Wb + (size_t)(n0 + nb*16 + lr) * DIM + k8);
      acc[nb] = __builtin_amdgcn_mfma_f32_16x16x32_bf16(a, bfr, acc[nb], 0, 0, 0);
    }
  }
  #pragma unroll
  for (int nb = 0; nb < 4; ++nb) {
    const int n = n0 + nb*16 + lr;
    const float bv = bias[n];
    #pragma unroll
    for (int r = 0; r < 4; ++r)
      tile[hi*4 + r][n] = f2bf(acc[nb][r] + bv);
  }
  __syncthreads();
  const int t = threadIdx.x;            // d index 0..255
  short8 lo8, hi8;
  #pragma unroll
  for (int k = 0; k < 8; ++k) { lo8[k] = tile[k][t]; hi8[k] = tile[k+8][t]; }
  const int b  = m0 >> 12;              // 4096 rows per batch
  const int k0 = m0 & (SKL - 1);
  short* p = outT + (size_t)b * DIM * SKL + (size_t)t * SKL + k0;
  *(short8*)(p)     = lo8;
  *(short8*)(p + 8) = hi8;
}

// ---------- flash attention: 4 waves/block, 32 q-rows/wave, KVB=64, dbuf + XOR swizzle ----------
__global__ __launch_bounds__(256, 1) void attn_kernel(
    const short* __restrict__ Qb, const short* __restrict__ Kb,
    const short* __restrict__ VtG, float* __restrict__ out)
{
  __shared__ alignas(16) short Kt[2][64][256];   // [buf][k][d], XOR-swizzled 16B slots
  __shared__ alignas(16) short Vt[2][256][64];   // [buf][d][k], XOR-swizzled
  __shared__ alignas(16) short Pl[4][32][64];    // per-wave P [q][k], XOR-swizzled

  const int tid  = threadIdx.x;
  const int lane = tid & 63;
  const int wave = tid >> 6;
  const int lr = lane & 15, hi = lane >> 4;

  const int b     = blockIdx.x & 7;     // batch -> XCD pinning (grid=256, 8 XCDs)
  const int qtile = blockIdx.x >> 3;
  const int q0w   = qtile * 128 + wave * 32;

  const short* Qp = Qb  + ((size_t)b * SQL + q0w) * DIM;
  const short* Kp = Kb  + (size_t)b * SKL * DIM;
  const short* Vp = VtG + (size_t)b * DIM * SKL;

  short8 qf0[8], qf1[8];
  #pragma unroll
  for (int kk = 0; kk < 8; ++kk) {
    qf0[kk] = *(const short8*)(Qp + (size_t)lr        * DIM + kk*32 + hi*8);
    qf1[kk] = *(const short8*)(Qp + (size_t)(16 + lr) * DIM + kk*32 + hi*8);
  }

  f32x4 o0[16], o1[16];
  #pragma unroll
  for (int i = 0; i < 16; ++i) { o0[i] = (f32x4)0.f; o1[i] = (f32x4)0.f; }
  float m0r[4] = {-3.0e38f,-3.0e38f,-3.0e38f,-3.0e38f};
  float m1r[4] = {-3.0e38f,-3.0e38f,-3.0e38f,-3.0e38f};
  float l0r[4] = {0.f,0.f,0.f,0.f};
  float l1r[4] = {0.f,0.f,0.f,0.f};

  // stage one KVB tile into buffer `buf`: linear LDS dest + inverse-swizzled global src
  auto stage = [&](int buf, int kv) {
    #pragma unroll
    for (int i = 0; i < 8; ++i) {
      const int row0 = wave*16 + i*2;
      const int row  = row0 + (lane >> 5);
      const int colb = ((lane & 31) * 16) ^ ((row & 7) << 4);
      gl_lds16((const char*)(Kp + (size_t)(kv + row) * DIM) + colb, (void*)&Kt[buf][row0][0]);
    }
    #pragma unroll
    for (int i = 0; i < 8; ++i) {
      const int d0 = wave*64 + i*8;
      const int d  = d0 + (lane >> 3);
      const int colb = ((lane & 7) * 16) ^ ((d & 7) << 4);
      gl_lds16((const char*)(Vp + (size_t)d * SKL + kv) + colb, (void*)&Vt[buf][d0][0]);
    }
  };

  stage(0, 0);
  __syncthreads();
  int cur = 0;

  const char* plw = (const char*)&Pl[wave][0][0];

  for (int it = 0; it < NIT; ++it) {
    // prefetch next tile into other buffer; latency hides under this whole iter
    if (it + 1 < NIT) stage(cur ^ 1, (it + 1) * KVB);

    // ---- QK^T: S[32q][64k], each Kt fragment feeds 2 MFMAs ----
    const char* ktb = (const char*)&Kt[cur][0][0];
    f32x4 s0[4], s1[4];
    #pragma unroll
    for (int ks = 0; ks < 4; ++ks) { s0[ks] = (f32x4)0.f; s1[ks] = (f32x4)0.f; }
    #pragma unroll
    for (int kk = 0; kk < 8; ++kk) {
      #pragma unroll
      for (int ks = 0; ks < 4; ++ks) {
        const int row = ks*16 + lr;
        short8 kf = *(const short8*)(ktb + row*512 + (((kk*64) + hi*16) ^ ((row & 7) << 4)));
        s0[ks] = __builtin_amdgcn_mfma_f32_16x16x32_bf16(qf0[kk], kf, s0[ks], 0, 0, 0);
        s1[ks] = __builtin_amdgcn_mfma_f32_16x16x32_bf16(qf1[kk], kf, s1[ks], 0, 0, 0);
      }
    }

    // ---- online softmax (row = hi*4+r, col = ks*16+lr) ----
    #pragma unroll
    for (int r = 0; r < 4; ++r) {
      {
        float mx = fmaxf(fmaxf(s0[0][r], s0[1][r]), fmaxf(s0[2][r], s0[3][r]));
        #pragma unroll
        for (int off = 8; off >= 1; off >>= 1) mx = fmaxf(mx, __shfl_xor(mx, off, 64));
        const float mn = fmaxf(m0r[r], mx);
        const float sc = __expf(m0r[r] - mn);
        m0r[r] = mn;
        const int row = hi*4 + r;
        float ps = 0.f;
        #pragma unroll
        for (int ks = 0; ks < 4; ++ks) {
          const float p = __expf(s0[ks][r] - mn);
          ps += p;
          *(short*)(plw + row*128 + ((2*(ks*16 + lr)) ^ ((row & 7) << 4))) = f2bf(p);
        }
        #pragma unroll
        for (int off = 8; off >= 1; off >>= 1) ps += __shfl_xor(ps, off, 64);
        l0r[r] = l0r[r] * sc + ps;
        #pragma unroll
        for (int dt = 0; dt < 16; ++dt) o0[dt][r] *= sc;
      }
      {
        float mx = fmaxf(fmaxf(s1[0][r], s1[1][r]), fmaxf(s1[2][r], s1[3][r]));
        #pragma unroll
        for (int off = 8; off >= 1; off >>= 1) mx = fmaxf(mx, __shfl_xor(mx, off, 64));
        const float mn = fmaxf(m1r[r], mx);
        const float sc = __expf(m1r[r] - mn);
        m1r[r] = mn;
        const int row = 16 + hi*4 + r;
        float ps = 0.f;
        #pragma unroll
        for (int ks = 0; ks < 4; ++ks) {
          const float p = __expf(s1[ks][r] - mn);
          ps += p;
          *(short*)(plw + row*128 + ((2*(ks*16 + lr)) ^ ((row & 7) << 4))) = f2bf(p);
        }
        #pragma unroll
        for (int off = 8; off >= 1; off >>= 1) ps += __shfl_xor(ps, off, 64);
        l1r[r] = l1r[r] * sc + ps;
        #pragma unroll
        for (int dt = 0; dt < 16; ++dt) o1[dt][r] *= sc;
      }
    }

    // ---- PV: O += P[32q][64k] . V[64k][256d]; each Vt fragment feeds 2 MFMAs ----
    const char* vtb = (const char*)&Vt[cur][0][0];
    short8 pa0[2], pa1[2];
    #pragma unroll
    for (int kh = 0; kh < 2; ++kh) {
      const int row0 = lr, row1 = 16 + lr;
      pa0[kh] = *(const short8*)(plw + row0*128 + ((kh*64 + hi*16) ^ ((row0 & 7) << 4)));
      pa1[kh] = *(const short8*)(plw + row1*128 + ((kh*64 + hi*16) ^ ((row1 & 7) << 4)));
    }
    #pragma unroll
    for (int dt = 0; dt < 16; ++dt) {
      #pragma unroll
      for (int kh = 0; kh < 2; ++kh) {
        const int d = dt*16 + lr;
        short8 vf = *(const short8*)(vtb + d*128 + ((kh*64 + hi*16) ^ ((d & 7) << 4)));
        o0[dt] = __builtin_amdgcn_mfma_f32_16x16x32_bf16(pa0[kh], vf, o0[dt], 0, 0, 0);
        o1[dt] = __builtin_amdgcn_mfma_f32_16x16x32_bf16(pa1[kh], vf, o1[dt], 0, 0, 0);
      }
    }

    __syncthreads();   // all waves done reading `cur`; prefetch into cur^1 drained
    cur ^= 1;
  }

  // ---- epilogue ----
  float* op = out + ((size_t)b * SQL + q0w) * DIM;
  #pragma unroll
  for (int r = 0; r < 4; ++r) {
    const float inv0 = 1.0f / l0r[r];
    const float inv1 = 1.0f / l1r[r];
    #pragma unroll
    for (int dt = 0; dt < 16; ++dt) {
      op[(size_t)(hi*4 + r) * DIM + dt*16 + lr]        = o0[dt][r] * inv0;
      op[(size_t)(16 + hi*4 + r) * DIM + dt*16 + lr]   = o1[dt][r] * inv1;
    }
  }
}

extern "C" void kernel_launch(void* const* d_in, const int* in_sizes, int n_in,
                              void* d_out, int out_size, void* d_ws, size_t ws_size,
                              hipStream_t stream) {
  const float* query  = (const float*)d_in[0];
  const float* keys   = (const float*)d_in[1];
  const float* values = (const float*)d_in[2];
  const float* Wq = (const float*)d_in[3];
  const float* bq = (const float*)d_in[4];
  const float* Wk = (const float*)d_in[5];
  const float* bk = (const float*)d_in[6];
  const float* Wv = (const float*)d_in[7];
  const float* bv = (const float*)d_in[8];
  float* out = (float*)d_out;

  const size_t elems = (size_t)BATCH * SQL * DIM;   // 8.39M per matrix
  short* Qb  = (short*)d_ws;
  short* Kb  = Qb + elems;
  short* VtT = Kb + elems;                          // [B][D][SK]

  // bf16 W storage: ws tail if it fits, else d_out tail (overwritten only after projections)
  const size_t wbytes = (size_t)3 * DIM * DIM * sizeof(short);
  short* Wb;
  if (ws_size >= 3 * elems * sizeof(short) + wbytes)
    Wb = VtT + elems;
  else
    Wb = (short*)((char*)d_out + (size_t)out_size * sizeof(float) - wbytes);
  short* Wqb = Wb;
  short* Wkb = Wb + DIM * DIM;
  short* Wvb = Wb + 2 * DIM * DIM;

  dim3 blk(256, 1, 1);
  wcvt_kernel <<<dim3(96, 1, 1),            blk, 0, stream>>>(Wq, Wk, Wv, Wb);
  proj_kernel <<<dim3(BATCH*SQL/16, 1, 1),  blk, 0, stream>>>(query,  Wqb, bq, Qb);
  proj_kernel <<<dim3(BATCH*SKL/16, 1, 1),  blk, 0, stream>>>(keys,   Wkb, bk, Kb);
  projV_kernel<<<dim3(BATCH*SKL/16, 1, 1),  blk, 0, stream>>>(values, Wvb, bv, VtT);
  attn_kernel <<<dim3(BATCH*SQL/128, 1, 1), blk, 0, stream>>>(Qb, Kb, VtT, out);
}

// Round 4
// 373.409 us; speedup vs baseline: 1.5315x; 1.4081x over previous
//
#include <hip/hip_runtime.h>
#include <hip/hip_bf16.h>
#include <math.h>

#define BATCH 8
#define SQL 4096
#define SKL 4096
#define DIM 256
#define KVB 64
#define NIT (SKL / KVB)

typedef __attribute__((ext_vector_type(8))) short short8;
typedef __attribute__((ext_vector_type(4))) float f32x4;
typedef __attribute__((ext_vector_type(4))) float floatx4;

typedef __attribute__((address_space(3))) unsigned int lds_uint;
typedef __attribute__((address_space(1))) unsigned int glob_uint;

__device__ __forceinline__ void gl_lds16(const void* g, void* l) {
  __builtin_amdgcn_global_load_lds((const glob_uint*)g, (lds_uint*)l, 16, 0, 0);
}

__device__ __forceinline__ short f2bf(float f) {
  union { float f; unsigned u; } x; x.f = f;
  unsigned r = x.u + 0x7fffu + ((x.u >> 16) & 1u);
  return (short)(r >> 16);
}

// ---------- W fp32 -> bf16, once ----------
__global__ __launch_bounds__(256) void wcvt_kernel(
    const float* __restrict__ W0, const float* __restrict__ W1,
    const float* __restrict__ W2, short* __restrict__ out)
{
  const int m = blockIdx.x >> 5;                       // 32 blocks per matrix
  const int i = ((blockIdx.x & 31) * 256 + threadIdx.x) * 8;
  const float* W = (m == 0) ? W0 : ((m == 1) ? W1 : W2);
  floatx4 a = *(const floatx4*)(W + i);
  floatx4 c = *(const floatx4*)(W + i + 4);
  short8 v;
  #pragma unroll
  for (int j = 0; j < 4; ++j) { v[j] = f2bf(a[j]); v[j+4] = f2bf(c[j]); }
  *(short8*)(out + (size_t)m * DIM * DIM + i) = v;
}

// ---------- projection: C[m,n] = X[m,:].Wb[n,:] + b[n], bf16 row-major out ----------
__global__ __launch_bounds__(256) void proj_kernel(
    const float* __restrict__ X, const short* __restrict__ Wb,
    const float* __restrict__ bias, short* __restrict__ out)
{
  const int lane = threadIdx.x & 63;
  const int wave = threadIdx.x >> 6;
  const int lr = lane & 15, hi = lane >> 4;
  const int m0 = blockIdx.x * 16;
  const int n0 = wave * 64;

  f32x4 acc[4] = {(f32x4)0.f, (f32x4)0.f, (f32x4)0.f, (f32x4)0.f};
  const float* xrow = X + (size_t)(m0 + lr) * DIM;

  #pragma unroll
  for (int kk = 0; kk < 8; ++kk) {
    const int k8 = kk * 32 + hi * 8;
    floatx4 xa = *(const floatx4*)(xrow + k8);
    floatx4 xb = *(const floatx4*)(xrow + k8 + 4);
    short8 a;
    #pragma unroll
    for (int j = 0; j < 4; ++j) { a[j] = f2bf(xa[j]); a[j+4] = f2bf(xb[j]); }
    #pragma unroll
    for (int nb = 0; nb < 4; ++nb) {
      short8 bfr = *(const short8*)(Wb + (size_t)(n0 + nb*16 + lr) * DIM + k8);
      acc[nb] = __builtin_amdgcn_mfma_f32_16x16x32_bf16(a, bfr, acc[nb], 0, 0, 0);
    }
  }
  #pragma unroll
  for (int nb = 0; nb < 4; ++nb) {
    const int n = n0 + nb*16 + lr;
    const float bv = bias[n];
    #pragma unroll
    for (int r = 0; r < 4; ++r) {
      const int m = m0 + hi*4 + r;
      out[(size_t)m * DIM + n] = f2bf(acc[nb][r] + bv);
    }
  }
}

// ---------- V projection, output TRANSPOSED: outT[b][d][k] ----------
__global__ __launch_bounds__(256) void projV_kernel(
    const float* __restrict__ X, const short* __restrict__ Wb,
    const float* __restrict__ bias, short* __restrict__ outT)
{
  __shared__ short tile[16][264];
  const int lane = threadIdx.x & 63;
  const int wave = threadIdx.x >> 6;
  const int lr = lane & 15, hi = lane >> 4;
  const int m0 = blockIdx.x * 16;
  const int n0 = wave * 64;

  f32x4 acc[4] = {(f32x4)0.f, (f32x4)0.f, (f32x4)0.f, (f32x4)0.f};
  const float* xrow = X + (size_t)(m0 + lr) * DIM;

  #pragma unroll
  for (int kk = 0; kk < 8; ++kk) {
    const int k8 = kk * 32 + hi * 8;
    floatx4 xa = *(const floatx4*)(xrow + k8);
    floatx4 xb = *(const floatx4*)(xrow + k8 + 4);
    short8 a;
    #pragma unroll
    for (int j = 0; j < 4; ++j) { a[j] = f2bf(xa[j]); a[j+4] = f2bf(xb[j]); }
    #pragma unroll
    for (int nb = 0; nb < 4; ++nb) {
      short8 bfr = *(const short8*)(Wb + (size_t)(n0 + nb*16 + lr) * DIM + k8);
      acc[nb] = __builtin_amdgcn_mfma_f32_16x16x32_bf16(a, bfr, acc[nb], 0, 0, 0);
    }
  }
  #pragma unroll
  for (int nb = 0; nb < 4; ++nb) {
    const int n = n0 + nb*16 + lr;
    const float bv = bias[n];
    #pragma unroll
    for (int r = 0; r < 4; ++r)
      tile[hi*4 + r][n] = f2bf(acc[nb][r] + bv);
  }
  __syncthreads();
  const int t = threadIdx.x;            // d index 0..255
  short8 lo8, hi8;
  #pragma unroll
  for (int k = 0; k < 8; ++k) { lo8[k] = tile[k][t]; hi8[k] = tile[k+8][t]; }
  const int b  = m0 >> 12;              // 4096 rows per batch
  const int k0 = m0 & (SKL - 1);
  short* p = outT + (size_t)b * DIM * SKL + (size_t)t * SKL + k0;
  *(short8*)(p)     = lo8;
  *(short8*)(p + 8) = hi8;
}

// ---------- flash attention: 8 waves/block (512 thr), 16 q-rows/wave, KVB=64, dbuf + XOR swizzle ----------
__global__ __launch_bounds__(512, 1) void attn_kernel(
    const short* __restrict__ Qb, const short* __restrict__ Kb,
    const short* __restrict__ VtG, float* __restrict__ out)
{
  __shared__ alignas(16) short Kt[2][64][256];   // [buf][k][d], XOR-swizzled 16B slots
  __shared__ alignas(16) short Vt[2][256][64];   // [buf][d][k], XOR-swizzled
  __shared__ alignas(16) short Pl[8][16][64];    // per-wave P [q][k], XOR-swizzled

  const int tid  = threadIdx.x;
  const int lane = tid & 63;
  const int wave = tid >> 6;                     // 0..7
  const int lr = lane & 15, hi = lane >> 4;

  const int b     = blockIdx.x & 7;     // batch -> XCD pinning (grid=256, 8 XCDs)
  const int qtile = blockIdx.x >> 3;
  const int q0w   = qtile * 128 + wave * 16;

  const short* Qp = Qb  + ((size_t)b * SQL + q0w) * DIM;
  const short* Kp = Kb  + (size_t)b * SKL * DIM;
  const short* Vp = VtG + (size_t)b * DIM * SKL;

  short8 qf[8];
  #pragma unroll
  for (int kk = 0; kk < 8; ++kk)
    qf[kk] = *(const short8*)(Qp + (size_t)lr * DIM + kk*32 + hi*8);

  f32x4 o[16];
  #pragma unroll
  for (int i = 0; i < 16; ++i) o[i] = (f32x4)0.f;
  float mr[4] = {-3.0e38f,-3.0e38f,-3.0e38f,-3.0e38f};
  float lsum[4] = {0.f,0.f,0.f,0.f};

  // stage one KVB tile: linear LDS dest + inverse-swizzled global src (8 waves share)
  auto stage = [&](int buf, int kv) {
    #pragma unroll
    for (int i = 0; i < 4; ++i) {
      const int row0 = wave*8 + i*2;
      const int row  = row0 + (lane >> 5);
      const int colb = ((lane & 31) * 16) ^ ((row & 7) << 4);
      gl_lds16((const char*)(Kp + (size_t)(kv + row) * DIM) + colb, (void*)&Kt[buf][row0][0]);
    }
    #pragma unroll
    for (int i = 0; i < 4; ++i) {
      const int d0 = wave*32 + i*8;
      const int d  = d0 + (lane >> 3);
      const int colb = ((lane & 7) * 16) ^ ((d & 7) << 4);
      gl_lds16((const char*)(Vp + (size_t)d * SKL + kv) + colb, (void*)&Vt[buf][d0][0]);
    }
  };

  stage(0, 0);
  __syncthreads();
  int cur = 0;

  const char* plw = (const char*)&Pl[wave][0][0];

  for (int it = 0; it < NIT; ++it) {
    // prefetch next tile into other buffer; latency hides under this whole iter
    if (it + 1 < NIT) stage(cur ^ 1, (it + 1) * KVB);

    // ---- QK^T: S[16q][64k] ----
    const char* ktb = (const char*)&Kt[cur][0][0];
    f32x4 s[4];
    #pragma unroll
    for (int ks = 0; ks < 4; ++ks) s[ks] = (f32x4)0.f;
    #pragma unroll
    for (int kk = 0; kk < 8; ++kk) {
      #pragma unroll
      for (int ks = 0; ks < 4; ++ks) {
        const int row = ks*16 + lr;
        short8 kf = *(const short8*)(ktb + row*512 + (((kk*64) + hi*16) ^ ((row & 7) << 4)));
        s[ks] = __builtin_amdgcn_mfma_f32_16x16x32_bf16(qf[kk], kf, s[ks], 0, 0, 0);
      }
    }

    // ---- online softmax (row = hi*4+r, col = ks*16+lr) ----
    float mx[4];
    #pragma unroll
    for (int r = 0; r < 4; ++r)
      mx[r] = fmaxf(fmaxf(s[0][r], s[1][r]), fmaxf(s[2][r], s[3][r]));
    #pragma unroll
    for (int off = 8; off >= 1; off >>= 1)
      #pragma unroll
      for (int r = 0; r < 4; ++r)
        mx[r] = fmaxf(mx[r], __shfl_xor(mx[r], off, 64));

    float ps[4];
    #pragma unroll
    for (int r = 0; r < 4; ++r) {
      const float mn = fmaxf(mr[r], mx[r]);
      const float sc = __expf(mr[r] - mn);
      mr[r] = mn;
      const int row = hi*4 + r;
      float acc = 0.f;
      #pragma unroll
      for (int ks = 0; ks < 4; ++ks) {
        const float p = __expf(s[ks][r] - mn);
        acc += p;
        *(short*)(plw + row*128 + ((2*(ks*16 + lr)) ^ ((row & 7) << 4))) = f2bf(p);
      }
      ps[r] = acc;
      lsum[r] *= sc;
      #pragma unroll
      for (int dt = 0; dt < 16; ++dt) o[dt][r] *= sc;
    }
    #pragma unroll
    for (int off = 8; off >= 1; off >>= 1)
      #pragma unroll
      for (int r = 0; r < 4; ++r)
        ps[r] += __shfl_xor(ps[r], off, 64);
    #pragma unroll
    for (int r = 0; r < 4; ++r) lsum[r] += ps[r];

    // ---- PV: O += P[16q][64k] . V[64k][256d] ----
    const char* vtb = (const char*)&Vt[cur][0][0];
    short8 pa[2];
    #pragma unroll
    for (int kh = 0; kh < 2; ++kh)
      pa[kh] = *(const short8*)(plw + lr*128 + ((kh*64 + hi*16) ^ ((lr & 7) << 4)));
    #pragma unroll
    for (int dt = 0; dt < 16; ++dt) {
      #pragma unroll
      for (int kh = 0; kh < 2; ++kh) {
        const int d = dt*16 + lr;
        short8 vf = *(const short8*)(vtb + d*128 + ((kh*64 + hi*16) ^ ((d & 7) << 4)));
        o[dt] = __builtin_amdgcn_mfma_f32_16x16x32_bf16(pa[kh], vf, o[dt], 0, 0, 0);
      }
    }

    __syncthreads();   // all waves done reading `cur`; prefetch into cur^1 drained
    cur ^= 1;
  }

  // ---- epilogue ----
  float* op = out + ((size_t)b * SQL + q0w) * DIM;
  #pragma unroll
  for (int r = 0; r < 4; ++r) {
    const float inv = 1.0f / lsum[r];
    #pragma unroll
    for (int dt = 0; dt < 16; ++dt)
      op[(size_t)(hi*4 + r) * DIM + dt*16 + lr] = o[dt][r] * inv;
  }
}

extern "C" void kernel_launch(void* const* d_in, const int* in_sizes, int n_in,
                              void* d_out, int out_size, void* d_ws, size_t ws_size,
                              hipStream_t stream) {
  const float* query  = (const float*)d_in[0];
  const float* keys   = (const float*)d_in[1];
  const float* values = (const float*)d_in[2];
  const float* Wq = (const float*)d_in[3];
  const float* bq = (const float*)d_in[4];
  const float* Wk = (const float*)d_in[5];
  const float* bk = (const float*)d_in[6];
  const float* Wv = (const float*)d_in[7];
  const float* bv = (const float*)d_in[8];
  float* out = (float*)d_out;

  const size_t elems = (size_t)BATCH * SQL * DIM;   // 8.39M per matrix
  short* Qb  = (short*)d_ws;
  short* Kb  = Qb + elems;
  short* VtT = Kb + elems;                          // [B][D][SK]

  // bf16 W storage: ws tail if it fits, else d_out tail (overwritten only after projections)
  const size_t wbytes = (size_t)3 * DIM * DIM * sizeof(short);
  short* Wb;
  if (ws_size >= 3 * elems * sizeof(short) + wbytes)
    Wb = VtT + elems;
  else
    Wb = (short*)((char*)d_out + (size_t)out_size * sizeof(float) - wbytes);
  short* Wqb = Wb;
  short* Wkb = Wb + DIM * DIM;
  short* Wvb = Wb + 2 * DIM * DIM;

  dim3 blk(256, 1, 1);
  dim3 blk512(512, 1, 1);
  wcvt_kernel <<<dim3(96, 1, 1),            blk, 0, stream>>>(Wq, Wk, Wv, Wb);
  proj_kernel <<<dim3(BATCH*SQL/16, 1, 1),  blk, 0, stream>>>(query,  Wqb, bq, Qb);
  proj_kernel <<<dim3(BATCH*SKL/16, 1, 1),  blk, 0, stream>>>(keys,   Wkb, bk, Kb);
  projV_kernel<<<dim3(BATCH*SKL/16, 1, 1),  blk, 0, stream>>>(values, Wvb, bv, VtT);
  attn_kernel <<<dim3(BATCH*SQL/128, 1, 1), blk512, 0, stream>>>(Qb, Kb, VtT, out);
}